// Round 6
// baseline (204.156 us; speedup 1.0000x reference)
//
#include <hip/hip_runtime.h>

#define CH 512
#define HEADS 4
#define HD 128
#define NPIX 1024
#define BATCH 16
#define GROUPS 32
#define GSZ 16
#define EPS 1e-5f

typedef _Float16 f16;
typedef _Float16 f16x8 __attribute__((ext_vector_type(8)));
typedef _Float16 f16x4 __attribute__((ext_vector_type(4)));
typedef _Float16 f16x2 __attribute__((ext_vector_type(2)));
typedef float f32x4 __attribute__((ext_vector_type(4)));
typedef float f32x16 __attribute__((ext_vector_type(16)));
typedef int i32x4 __attribute__((ext_vector_type(4)));

__device__ __forceinline__ void gld16(const f16* g, f16* l) {
    __builtin_amdgcn_global_load_lds((__attribute__((address_space(1))) const void*)g,
                                     (__attribute__((address_space(3))) void*)l, 16, 0, 0);
}

__device__ __forceinline__ int packf16(float lo, float hi) {
    f16x2 t; t[0] = (f16)lo; t[1] = (f16)hi;
    return __builtin_bit_cast(int, t);
}

// Build PV B-fragment (k=s4*16+halfl*8+j, col=l31) from QK^T C-layout P values
// (k-row=(reg&3)+8*(reg>>2)+4*halfl, col=l31), 8 regs [base,base+8).
// Exchange across the lane<32/lane>=32 split via __shfl_xor(.,32) (unambiguous,
// proven in-kernel by the softmax shuffles) + halfl-select:
//   h0 frag = [own(p0,p1),(p2,p3), partner(p0,p1),(p2,p3)]   (k 0..7 of block)
//   h1 frag = [partner(p4,p5),(p6,p7), own(p4,p5),(p6,p7)]   (k 8..15 of block)
__device__ __forceinline__ f16x8 mkfrag(const f32x16& s, int base, int halfl) {
    int a0 = packf16(s[base + 0], s[base + 1]);
    int a1 = packf16(s[base + 2], s[base + 3]);
    int b0 = packf16(s[base + 4], s[base + 5]);
    int b1 = packf16(s[base + 6], s[base + 7]);
    int xa0 = __shfl_xor(a0, 32);
    int xa1 = __shfl_xor(a1, 32);
    int xb0 = __shfl_xor(b0, 32);
    int xb1 = __shfl_xor(b1, 32);
    i32x4 fw;
    fw.x = halfl ? xb0 : a0;
    fw.y = halfl ? xb1 : a1;
    fw.z = halfl ? b0 : xa0;
    fw.w = halfl ? b1 : xa1;
    return __builtin_bit_cast(f16x8, fw);
}

// ---------------- K1: fused [groupnorm+transpose | weight-convert] ----------------
// blocks 0..511: groupnorm (one per (g,b)); blocks 512..895: weight pre-transpose.
__global__ __launch_bounds__(256, 2) void k_pre(const float* __restrict__ x, const float* __restrict__ gamma,
                                                const float* __restrict__ beta, f16* __restrict__ xnT,
                                                const float* __restrict__ wq, const float* __restrict__ wp,
                                                f16* __restrict__ wqT, f16* __restrict__ wpT) {
    __shared__ float xs[GSZ * NPIX];   // 64 KB
    __shared__ float red[8];
    __shared__ float stat2[2];
    int bidx = blockIdx.x;
    if (bidx >= 512) {
        // ---- weight convert branch ----
        int c = (bidx - 512) * 256 + threadIdx.x;
        {
            int ot = c >> 13, kbl = (c >> 7) & 63, ol = c & 127;
            const float* s = wq + ((size_t)(ot * 128 + ol)) * CH + kbl * 8;
            f32x4 a = *(const f32x4*)s, b2 = *(const f32x4*)(s + 4);
            f16x8 v;
            v[0] = (f16)a.x; v[1] = (f16)a.y; v[2] = (f16)a.z; v[3] = (f16)a.w;
            v[4] = (f16)b2.x; v[5] = (f16)b2.y; v[6] = (f16)b2.z; v[7] = (f16)b2.w;
            *(f16x8*)(wqT + (size_t)c * 8) = v;
        }
        if (c < 32768) {
            int ot = c >> 13, kbl = (c >> 7) & 63, ol = c & 127;
            const float* s = wp + ((size_t)(ot * 128 + ol)) * CH + kbl * 8;
            f32x4 a = *(const f32x4*)s, b2 = *(const f32x4*)(s + 4);
            f16x8 v;
            v[0] = (f16)a.x; v[1] = (f16)a.y; v[2] = (f16)a.z; v[3] = (f16)a.w;
            v[4] = (f16)b2.x; v[5] = (f16)b2.y; v[6] = (f16)b2.z; v[7] = (f16)b2.w;
            *(f16x8*)(wpT + (size_t)c * 8) = v;
        }
        return;
    }
    // ---- groupnorm branch ----
    int g = bidx & 31, b = bidx >> 5;
    const f32x4* x4 = (const f32x4*)(x + ((size_t)(b * GROUPS + g)) * (GSZ * NPIX));
    float s = 0.f, ss = 0.f;
    for (int i = threadIdx.x; i < GSZ * NPIX / 4; i += 256) {
        f32x4 v = x4[i];
        *(f32x4*)&xs[i * 4] = v;
        s  += v.x + v.y + v.z + v.w;
        ss += v.x * v.x + v.y * v.y + v.z * v.z + v.w * v.w;
    }
    for (int off = 32; off; off >>= 1) { s += __shfl_down(s, off); ss += __shfl_down(ss, off); }
    int wv = threadIdx.x >> 6, ln = threadIdx.x & 63;
    if (ln == 0) { red[wv] = s; red[4 + wv] = ss; }
    __syncthreads();
    if (threadIdx.x == 0) {
        float S = red[0] + red[1] + red[2] + red[3];
        float SS = red[4] + red[5] + red[6] + red[7];
        float mu = S / (GSZ * NPIX);
        float var = SS / (GSZ * NPIX) - mu * mu;
        stat2[0] = mu; stat2[1] = rsqrtf(var + EPS);
    }
    __syncthreads();
    float mu = stat2[0], rstd = stat2[1];
    int ch = threadIdx.x >> 7;
    int n  = threadIdx.x & 127;
    float gl[8], bl[8];
#pragma unroll
    for (int i = 0; i < 8; i++) {
        float gv = gamma[g * 16 + ch * 8 + i] * rstd;
        gl[i] = gv;
        bl[i] = beta[g * 16 + ch * 8 + i] - mu * gv;
    }
    f16* tb0 = xnT + ((size_t)(b * 8)) * 65536 + (g * 2 + ch) * 1024 + n * 8;
#pragma unroll
    for (int nt = 0; nt < 8; nt++) {
        f16x8 o;
#pragma unroll
        for (int i = 0; i < 8; i++)
            o[i] = (f16)(xs[(ch * 8 + i) * 1024 + nt * 128 + n] * gl[i] + bl[i]);
        *(f16x8*)(tb0 + (size_t)nt * 65536) = o;
    }
}

// ---------------- K2: QKV GEMM v1 (R10-measured), BK=64, gld16, 3 blocks/CU ----------------
__global__ __launch_bounds__(256, 3) void k_qkv(const f16* __restrict__ wT, const float* __restrict__ bias,
                                                const f16* __restrict__ xnT, f16* __restrict__ qF,
                                                f16* __restrict__ kTl, f16* __restrict__ vTl) {
    int nt = blockIdx.x, ot = blockIdx.y, b = blockIdx.z;
    int o0 = ot * 128;
    __shared__ union SM {
        struct { f16 As[8192]; f16 Bs[8192]; } s;
        f16 Cf[16384];
    } sm;
    __shared__ float biasS[128];
    if (threadIdx.x < 128) biasS[threadIdx.x] = bias[o0 + threadIdx.x];
    int tid = threadIdx.x, lane = tid & 63, wv = tid >> 6;
    int wr = wv >> 1, wc = wv & 1;
    int l15 = lane & 15, quad = lane >> 4;
    const f16* wA = wT + (size_t)ot * 65536;
    const f16* xB = xnT + ((size_t)(b * 8 + nt)) * 65536;
    f32x4 acc[4][4] = {};
    for (int kk = 0; kk < CH; kk += 64) {
        __syncthreads();
        const f16* sa = wA + (size_t)(kk >> 3) * 1024;
        const f16* sb = xB + (size_t)(kk >> 3) * 1024;
#pragma unroll
        for (int i = 0; i < 4; i++) {
            int s = wv * 4 + i;
            gld16(sa + (size_t)(s * 64 + lane) * 8, sm.s.As + s * 512);
            gld16(sb + (size_t)(s * 64 + lane) * 8, sm.s.Bs + s * 512);
        }
        __syncthreads();
#pragma unroll
        for (int dk = 0; dk < 2; dk++) {
            f16x8 af[4], bf[4];
#pragma unroll
            for (int t = 0; t < 4; t++) {
                af[t] = *(const f16x8*)(sm.s.As + (dk * 4 + quad) * 1024 + (wr * 64 + t * 16 + l15) * 8);
                bf[t] = *(const f16x8*)(sm.s.Bs + (dk * 4 + quad) * 1024 + (wc * 64 + t * 16 + l15) * 8);
            }
#pragma unroll
            for (int tm = 0; tm < 4; tm++)
#pragma unroll
                for (int tn = 0; tn < 4; tn++)
                    acc[tm][tn] = __builtin_amdgcn_mfma_f32_16x16x32_f16(af[tm], bf[tn], acc[tm][tn], 0, 0, 0);
        }
    }
    __syncthreads();
    int which = ot >> 2, h = ot & 3;
#pragma unroll
    for (int tm = 0; tm < 4; tm++)
#pragma unroll
        for (int tn = 0; tn < 4; tn++) {
            int ob = wr * 64 + tm * 16 + quad * 4;
            int n  = wc * 64 + tn * 16 + l15;
            f16x4 pv;
#pragma unroll
            for (int r = 0; r < 4; r++) pv[r] = (f16)(acc[tm][tn][r] + biasS[ob + r]);
            if (which == 0) {
                int addr = ((((n >> 5) * 2 + ((n >> 4) & 1)) * 4 + (ob >> 5)) * 512)
                         + ((ob >> 3) & 3) * 128 + (n & 15) * 8 + (quad & 1) * 4;
                *(f16x4*)&sm.Cf[addr] = pv;
            } else if (which == 1) {
                int addr = (ob >> 3) * 1024 + n * 8 + (quad & 1) * 4;
                *(f16x4*)&sm.Cf[addr] = pv;
            } else {
#pragma unroll
                for (int r = 0; r < 4; r++)
                    sm.Cf[(n >> 3) * 1024 + (ob + r) * 8 + (n & 7)] = pv[r];
            }
        }
    __syncthreads();
    f16* tb = (which == 0) ? (qF + ((size_t)((b * 4 + h) * 8 + nt)) * 16384)
            : (which == 1) ? (kTl + ((size_t)((b * 4 + h) * 8 + nt)) * 16384)
                           : (vTl + ((size_t)((b * 4 + h) * 8 + nt)) * 16384);
#pragma unroll
    for (int i = 0; i < 8; i++) {
        int cid = tid + i * 256;
        *(f16x8*)(tb + (size_t)cid * 8) = *(const f16x8*)(sm.Cf + cid * 8);
    }
}

// ---------------- K3: flash attention v13 — v10 + in-register P (shfl_xor) ----------------
// Minimal diff on the PASSING v10 (50 us): the wave-private P LDS round-trip
// (8 ds_write + 4 ds_read + lgkm waits on the softmax->PV critical path) is replaced
// by in-register fragment construction using __shfl_xor(.,32) + halfl-select —
// semantics proven in-kernel (softmax shuffles cross the 32-lane boundary already).
// Double-buffered K/V with gld16 + 1 barrier/iter is untouched. LDS 80 -> 64 KB.
// Occupancy is grid-capped (512 blocks / 256 CU = 2 blocks/CU) — the lever here is
// the shorter per-iteration serial chain, not waves.
__global__ __launch_bounds__(256, 2) void k_attn(const f16* __restrict__ qF, const f16* __restrict__ kTl,
                                                 const f16* __restrict__ vTl, f16* __restrict__ oT) {
    extern __shared__ f16 smem[];   // [0,16384) buf0 K|V ; [16384,32768) buf1 K|V
    int bid = blockIdx.x;
    int nt = bid >> 6, group = bid & 63;
    int b = group >> 2, h = group & 3;
    int tid = threadIdx.x, lane = tid & 63, wv = tid >> 6;   // wv 0..3
    int l31 = lane & 31, halfl = lane >> 5;
    const f16* qb = qF + ((size_t)(group * 8 + nt)) * 16384;
    const f16* kb = kTl + (size_t)group * 8 * 16384;
    const f16* vb = vTl + (size_t)group * 8 * 16384;

    // Q as B-fragments for 32x32x16: col q = wv*32 + l31, k(d) = s*16 + halfl*8 + j
    f16x8 aq[8];
    {
        int bq = (wv * 2 + ((lane >> 4) & 1)) * 4;
#pragma unroll
        for (int s = 0; s < 8; s++) {
            f16x8 v = *(const f16x8*)(qb + (bq + (s >> 1)) * 512 + ((s & 1) * 2 + halfl) * 128 + (lane & 15) * 8);
            aq[s] = v * (f16)(0.08838834764831845f * 1.4426950408889634f);
        }
    }

    float m_i = -1e30f, l_i = 0.f;
    f32x16 oacc[4] = {};   // O^T: 4 d-tiles of 32, col q

    // stage K/V tile mc into buffer (wave 0,1: K ; wave 2,3: V), pure gld16
    auto stage = [&](int mc, f16* dst) {
        if (wv < 2) {
            const f16* src = kb + (size_t)(mc >> 1) * 16384 + (size_t)(mc & 1) * 512;
#pragma unroll
            for (int i = 0; i < 8; i++)
                gld16(src + (size_t)(wv * 8 + i) * 1024 + lane * 8, dst + (wv * 8 + i) * 512);
        } else {
            const f16* src = vb + (size_t)mc * 8192;
#pragma unroll
            for (int i = 0; i < 8; i++)
                gld16(src + (size_t)((wv - 2) * 8 + i) * 512 + lane * 8, dst + 8192 + ((wv - 2) * 8 + i) * 512);
        }
    };

    stage(0, smem);

    for (int mc = 0; mc < 16; mc++) {
        __syncthreads();                 // implicit vmcnt(0): tile mc resident, prior reads done
        f16* Kc = smem + (mc & 1) * 16384;
        f16* Vc = Kc + 8192;
        if (mc < 15) stage(mc + 1, smem + ((mc + 1) & 1) * 16384);

        // S^T = K Q^T : two 32x32 k-tiles, A = K (row=kpix, k=d), B = Q
        f32x16 st0 = {}, st1 = {};
#pragma unroll
        for (int s = 0; s < 8; s++) {
            f16x8 k0 = *(const f16x8*)&Kc[(s * 2 + halfl) * 512 + l31 * 8];
            f16x8 k1 = *(const f16x8*)&Kc[(s * 2 + halfl) * 512 + (32 + l31) * 8];
            st0 = __builtin_amdgcn_mfma_f32_32x32x16_f16(k0, aq[s], st0, 0, 0, 0);
            st1 = __builtin_amdgcn_mfma_f32_32x32x16_f16(k1, aq[s], st1, 0, 0, 0);
        }

        // online softmax (exp2 domain): in-lane tree over 32 vals + ONE shfl_xor(32)
        float a[16];
#pragma unroll
        for (int i = 0; i < 16; i++) a[i] = fmaxf(st0[i], st1[i]);
#pragma unroll
        for (int i = 0; i < 8; i++) a[i] = fmaxf(a[i], a[i + 8]);
#pragma unroll
        for (int i = 0; i < 4; i++) a[i] = fmaxf(a[i], a[i + 4]);
        float mx = fmaxf(fmaxf(a[0], a[1]), fmaxf(a[2], a[3]));
        mx = fmaxf(mx, __shfl_xor(mx, 32));

        bool full = !__all(mx <= m_i + 8.f);
        float mnew = m_i, alpha = 1.f;
        if (full) {
            mnew = fmaxf(m_i, mx);
            alpha = __builtin_amdgcn_exp2f(m_i - mnew);
            m_i = mnew;
        }

        float r[16];
#pragma unroll
        for (int i = 0; i < 16; i++) {
            float p0 = __builtin_amdgcn_exp2f(st0[i] - mnew);
            float p1 = __builtin_amdgcn_exp2f(st1[i] - mnew);
            st0[i] = p0; st1[i] = p1;
            r[i] = p0 + p1;
        }
#pragma unroll
        for (int i = 0; i < 8; i++) r[i] += r[i + 8];
#pragma unroll
        for (int i = 0; i < 4; i++) r[i] += r[i + 4];
        float rs = (r[0] + r[1]) + (r[2] + r[3]);
        rs += __shfl_xor(rs, 32);
        if (full) {
            l_i = l_i * alpha + rs;
#pragma unroll
            for (int dt = 0; dt < 4; dt++)
#pragma unroll
                for (int i = 0; i < 16; i++) oacc[dt][i] *= alpha;
        } else {
            l_i += rs;
        }

        // P -> PV B-fragments entirely in registers (shfl_xor exchange, no LDS)
        f16x8 pfr[4];
        pfr[0] = mkfrag(st0, 0, halfl);
        pfr[1] = mkfrag(st0, 8, halfl);
        pfr[2] = mkfrag(st1, 0, halfl);
        pfr[3] = mkfrag(st1, 8, halfl);

        // O^T += V^T P : A = V^T (row=d, k=kpix), B = P (registers)
#pragma unroll
        for (int s4 = 0; s4 < 4; s4++) {
#pragma unroll
            for (int dt = 0; dt < 4; dt++) {
                f16x8 vf = *(const f16x8*)&Vc[(s4 * 2 + halfl) * 1024 + (dt * 32 + l31) * 8];
                oacc[dt] = __builtin_amdgcn_mfma_f32_32x32x16_f16(vf, pfr[s4], oacc[dt], 0, 0, 0);
            }
        }
    }

    // epilogue: stage O (128 d x 128 q) into smem[0,16384) with XOR swizzle, then coalesced store
    __syncthreads();
    {
        float inv = 1.f / l_i;
        int n = wv * 32 + l31;
#pragma unroll
        for (int dt = 0; dt < 4; dt++)
#pragma unroll
            for (int g = 0; g < 4; g++) {
                f16x4 ov;
#pragma unroll
                for (int rr = 0; rr < 4; rr++) ov[rr] = (f16)(oacc[dt][g * 4 + rr] * inv);
                int cbl = dt * 4 + g;   // d-block of 8 (base d = dt*32 + g*8 + halfl*4)
                *(f16x4*)&smem[n * 128 + ((cbl ^ (n & 15)) << 3) + (halfl << 2)] = ov;
            }
    }
    __syncthreads();
    f16* ob = oT + ((size_t)(b * 8 + nt)) * 65536;
#pragma unroll
    for (int i = 0; i < 8; i++) {
        int cid = tid + i * 256;
        int cbl = cid >> 7, n = cid & 127;
        f16x8 v = *(const f16x8*)&smem[n * 128 + ((cbl ^ (n & 15)) << 3)];
        *(f16x8*)(ob + (size_t)(h * 16 + cbl) * 1024 + n * 8) = v;
    }
}

// ---------------- K4: proj GEMM + bias + residual -> fp32 out ----------------
__global__ __launch_bounds__(256, 3) void k_proj(const f16* __restrict__ wT, const float* __restrict__ bias,
                                                 const f16* __restrict__ oT, const float* __restrict__ x,
                                                 float* __restrict__ out) {
    int nt = blockIdx.x, ot = blockIdx.y, b = blockIdx.z;
    int n0 = nt * 128, o0 = ot * 128;
    __shared__ union SM {
        struct { f16 As[8192]; f16 Bs[8192]; } s;
        f16 Cs[128][136];
    } sm;
    __shared__ float biasS[128];
    if (threadIdx.x < 128) biasS[threadIdx.x] = bias[o0 + threadIdx.x];
    int tid = threadIdx.x, lane = tid & 63, wv = tid >> 6;
    int wr = wv >> 1, wc = wv & 1;
    int l15 = lane & 15, quad = lane >> 4;
    const f16* wA = wT + (size_t)ot * 65536;
    const f16* xB = oT + ((size_t)(b * 8 + nt)) * 65536;
    f32x4 acc[4][4] = {};
    for (int kk = 0; kk < CH; kk += 64) {
        __syncthreads();
        const f16* sa = wA + (size_t)(kk >> 3) * 1024;
        const f16* sb = xB + (size_t)(kk >> 3) * 1024;
#pragma unroll
        for (int i = 0; i < 4; i++) {
            int s = wv * 4 + i;
            gld16(sa + (size_t)(s * 64 + lane) * 8, sm.s.As + s * 512);
            gld16(sb + (size_t)(s * 64 + lane) * 8, sm.s.Bs + s * 512);
        }
        __syncthreads();
#pragma unroll
        for (int dk = 0; dk < 2; dk++) {
            f16x8 af[4], bf[4];
#pragma unroll
            for (int t = 0; t < 4; t++) {
                af[t] = *(const f16x8*)(sm.s.As + (dk * 4 + quad) * 1024 + (wr * 64 + t * 16 + l15) * 8);
                bf[t] = *(const f16x8*)(sm.s.Bs + (dk * 4 + quad) * 1024 + (wc * 64 + t * 16 + l15) * 8);
            }
#pragma unroll
            for (int tm = 0; tm < 4; tm++)
#pragma unroll
                for (int tn = 0; tn < 4; tn++)
                    acc[tm][tn] = __builtin_amdgcn_mfma_f32_16x16x32_f16(af[tm], bf[tn], acc[tm][tn], 0, 0, 0);
        }
    }
    __syncthreads();
#pragma unroll
    for (int tm = 0; tm < 4; tm++)
#pragma unroll
        for (int tn = 0; tn < 4; tn++)
#pragma unroll
            for (int r = 0; r < 4; r++) {
                int o = wr * 64 + tm * 16 + quad * 4 + r;
                int n = wc * 64 + tn * 16 + l15;
                sm.Cs[o][n] = (f16)(acc[tm][tn][r] + biasS[o]);
            }
    __syncthreads();
#pragma unroll
    for (int i = 0; i < 8; i++) {
        int cid = tid + i * 256;
        int row = cid >> 4, off = (cid & 15) * 8;
        f16x8 v = *(const f16x8*)&sm.Cs[row][off];
        size_t gofs = ((size_t)(b * CH) + o0 + row) * NPIX + n0 + off;
        const float* xp = x + gofs;
        float* op = out + gofs;
        f32x4 o0v, o1v;
        o0v.x = xp[0] + (float)v[0]; o0v.y = xp[1] + (float)v[1];
        o0v.z = xp[2] + (float)v[2]; o0v.w = xp[3] + (float)v[3];
        o1v.x = xp[4] + (float)v[4]; o1v.y = xp[5] + (float)v[5];
        o1v.z = xp[6] + (float)v[6]; o1v.w = xp[7] + (float)v[7];
        *(f32x4*)op = o0v; *(f32x4*)(op + 4) = o1v;
    }
}

extern "C" void kernel_launch(void* const* d_in, const int* in_sizes, int n_in,
                              void* d_out, int out_size, void* d_ws, size_t ws_size,
                              hipStream_t stream) {
    const float* x     = (const float*)d_in[0];
    const float* gamma = (const float*)d_in[1];
    const float* beta  = (const float*)d_in[2];
    const float* wqkv  = (const float*)d_in[3];
    const float* bqkv  = (const float*)d_in[4];
    const float* wproj = (const float*)d_in[5];
    const float* bproj = (const float*)d_in[6];
    float* out = (float*)d_out;

    char* p = (char*)d_ws;
    f16* wqT = (f16*)p;           p += (size_t)3 * CH * CH * 2;
    f16* wpT = (f16*)p;           p += (size_t)CH * CH * 2;
    f16* xnT = (f16*)p;           p += (size_t)BATCH * NPIX * CH * 2;
    f16* qF  = (f16*)p;           p += (size_t)BATCH * HEADS * NPIX * HD * 2;
    f16* kTl = (f16*)p;           p += (size_t)BATCH * HEADS * NPIX * HD * 2;
    f16* vTl = (f16*)p;           p += (size_t)BATCH * HEADS * NPIX * HD * 2;
    f16* oT  = (f16*)p;           p += (size_t)BATCH * NPIX * CH * 2;

    k_pre<<<dim3(896), 256, 0, stream>>>(x, gamma, beta, xnT, wqkv, wproj, wqT, wpT);
    k_qkv<<<dim3(8, 12, BATCH), 256, 0, stream>>>(wqT, bqkv, xnT, qF, kTl, vTl);

    hipFuncSetAttribute((const void*)k_attn, hipFuncAttributeMaxDynamicSharedMemorySize, 65536);
    k_attn<<<dim3(512), 256, 65536, stream>>>(qF, kTl, vTl, oT);

    k_proj<<<dim3(8, 4, BATCH), 256, 0, stream>>>(wpT, bproj, oT, x, out);
}